// Round 12
// baseline (146.806 us; speedup 1.0000x reference)
//
#include <hip/hip_runtime.h>
#include <hip/hip_bf16.h>
#include <hip/hip_fp16.h>

#define T_ 4096
#define C_ 1024
#define H_ 64
#define LSTR 72    // P-buffer LDS row stride (bf16 elems)
#define XBS 1032   // x-tile LDS row stride (bf16 elems): mult-8 (16B align), 4-way banks max

typedef short bf16x8 __attribute__((ext_vector_type(8)));
typedef float f32x4 __attribute__((ext_vector_type(4)));

__device__ __forceinline__ short f2bf(float f) {
  union { __hip_bfloat16 h; short s; } u;
  u.h = __float2bfloat16(f);
  return u.s;
}
__device__ __forceinline__ unsigned pack2(float a, float b) {
  return ((unsigned)(unsigned short)f2bf(b) << 16) | (unsigned short)f2bf(a);
}

// async global->LDS, 16B per lane; LDS dest = wave-uniform base + lane*16.
__device__ __forceinline__ void stage16(const __hip_bfloat16* g,
                                        __hip_bfloat16* l) {
  __builtin_amdgcn_global_load_lds(
      (const __attribute__((address_space(1))) unsigned*)g,
      (__attribute__((address_space(3))) unsigned*)l, 16, 0, 0);
}

// ---- kernel 0: W[c][h] fp32 -> Wtf in MFMA B-FRAG ORDER (R3-verified).
__global__ void wtrans_kernel(const float* __restrict__ Wk,
                              const float* __restrict__ Wq,
                              const float* __restrict__ Wv,
                              __hip_bfloat16* __restrict__ Wtf) {
  int tid = blockIdx.x * 256 + threadIdx.x;  // 0..196607 exact
  const int j = tid & 7;
  const int lane = (tid >> 3) & 63;
  const int m = lane & 15;
  const int quad = lane >> 4;
  const int f = (tid >> 9) & 15;
  const int nt = f & 3;
  const int ks = f >> 2;
  const int c = (tid >> 13) & 7;
  const int which = tid >> 16;
  const float* W = (which == 0) ? Wk : ((which == 1) ? Wq : Wv);
  const int cc = c * 128 + ks * 32 + quad * 8 + j;
  const int h = nt * 16 + m;
  Wtf[tid] = __float2bfloat16(W[cc * 64 + h]);
}

// ---- kernel 1: qkv projection (exact R0 known-good version).
__global__ __launch_bounds__(256) void proj_kernel(
    const float* __restrict__ x, const __hip_bfloat16* __restrict__ Wtf,
    __hip_bfloat16* __restrict__ qb, __hip_bfloat16* __restrict__ Kf,
    __hip_bfloat16* __restrict__ Vf) {
  __shared__ __hip_bfloat16 Xb[16 * XBS];
  const int tid = threadIdx.x;
  const int lane = tid & 63;
  const int wave = tid >> 6;
  const int m = lane & 15;
  const int quad = lane >> 4;
  const int t0 = blockIdx.x * 16;

  // ---- phase 1: stage x-tile (contiguous 4096 float4), convert to bf16
  const float4* xtile = (const float4*)(x + (size_t)t0 * C_);
  float4 xv[16];
#pragma unroll
  for (int k = 0; k < 16; ++k) xv[k] = xtile[tid + k * 256];
#pragma unroll
  for (int k = 0; k < 16; ++k) {
    const int idx = tid + k * 256;
    const int row = idx >> 8;      // 256 float4 per row
    const int c4 = idx & 255;
    uint2 u = {pack2(xv[k].x, xv[k].y), pack2(xv[k].z, xv[k].w)};
    *(uint2*)(&Xb[row * XBS + c4 * 4]) = u;
  }
  __syncthreads();

  // ---- phase 2: wave owns output-tiles g = 3*wave .. 3*wave+2
  int whichs[3], ntls[3];
  const __hip_bfloat16* wb[3];
#pragma unroll
  for (int i = 0; i < 3; ++i) {
    const int g = wave * 3 + i;
    whichs[i] = g >> 2;
    ntls[i] = g & 3;
    wb[i] = Wtf + (size_t)whichs[i] * 65536 + ntls[i] * 512 + lane * 8;
  }
  f32x4 acc[3];
#pragma unroll
  for (int i = 0; i < 3; ++i) acc[i] = (f32x4){0.f, 0.f, 0.f, 0.f};

#pragma unroll
  for (int c = 0; c < 8; ++c) {
    bf16x8 bq[12];
#pragma unroll
    for (int i = 0; i < 3; ++i)
#pragma unroll
      for (int ks = 0; ks < 4; ++ks)
        bq[i * 4 + ks] = *(const bf16x8*)(wb[i] + (c * 16 + ks * 4) * 512);
#pragma unroll
    for (int ks = 0; ks < 4; ++ks) {
      bf16x8 a = *(const bf16x8*)(&Xb[m * XBS + c * 128 + ks * 32 + quad * 8]);
#pragma unroll
      for (int i = 0; i < 3; ++i)
        acc[i] = __builtin_amdgcn_mfma_f32_16x16x32_bf16(a, bq[i * 4 + ks],
                                                         acc[i], 0, 0, 0);
    }
  }

  // ---- stores
  const int bb = t0 >> 12;
  const int tloc = t0 & (T_ - 1);
  const int ktile = tloc >> 6;
  const float cscale = 0.18033688011112042f;  // log2(e)/sqrt(64)

#pragma unroll
  for (int i = 0; i < 3; ++i) {
    const int which = whichs[i];
    const int ntl = ntls[i];
    if (which == 1) {  // Q: row-major [t][h], PRE-SCALED into exp2 domain
#pragma unroll
      for (int r = 0; r < 4; ++r)
        qb[(size_t)(t0 + quad * 4 + r) * H_ + ntl * 16 + m] =
            __float2bfloat16(acc[i][r] * cscale);
    } else if (which == 0) {  // K -> frag order (R3-verified swizzle)
      __hip_bfloat16* dst = Kf + ((size_t)bb * 64 + ktile) * 4096;
      const int ntK = (tloc >> 4) & 3;
      const int wh = ntl >> 1;
      const int quadK = (ntl * 2 + (m >> 3)) & 3;
      const int j = m & 7;
#pragma unroll
      for (int r = 0; r < 4; ++r) {
        const int mK = quad * 4 + r;
        dst[(ntK * 2 + wh) * 512 + (quadK * 16 + mK) * 8 + j] =
            __float2bfloat16(acc[i][r]);
      }
    } else {  // V -> frag order (R3-verified swizzle)
      __hip_bfloat16* dst = Vf + ((size_t)bb * 64 + ktile) * 4096;
#pragma unroll
      for (int r = 0; r < 4; ++r) {
        const int kvo = (tloc & 63) + quad * 4 + r;
        const int half = (kvo >> 5) & 1;
        const int quadV = (kvo >> 3) & 3;
        const int j = kvo & 7;
        dst[(ntl * 2 + half) * 512 + (quadV * 16 + m) * 8 + j] =
            __float2bfloat16(acc[i][r]);
      }
    }
  }
}

// ---- kernel 2: flash pass1 v11 (R12): exact R8 loop (champion structure:
// K-only dbuf, V direct per-wave reads, 1 barrier/iter) with two deltas:
//  (1) __launch_bounds__(256, 6): arg2 = BLOCKS/CU (R10/R11-calibrated).
//      LDS 25.6KB*6 = 153.6 <= 160KB; VGPR cap 512/6 ~= 85 >= ~60 needed.
//      20 -> 24 waves/CU: tests the latency-bound theory (traffic theory is
//      dead: R3/R9/R11 all cut traffic 4-5x with zero or negative gain).
//  (2) nc==1 (g==0, qt<32) jobs write OUT directly, normalized in-register
//      via shfl transpose (R4-verified code path; no fence needed for
//      single-chunk tiles). Combine shrinks to qt>=32 (896 blocks).
__global__ __launch_bounds__(256, 6) void fa_pass1(
    const __hip_bfloat16* __restrict__ qg, const __hip_bfloat16* __restrict__ Kf,
    const __hip_bfloat16* __restrict__ Vf, __half* __restrict__ Opart,
    __half* __restrict__ Ml, float* __restrict__ out) {
  __shared__ __align__(16) __hip_bfloat16 Kl[2][4096];  // K tile dbuf, 8KB each
  __shared__ __hip_bfloat16 Pl[4][16 * LSTR];           // P[q=16][kv=64] per wave
  const int lane = threadIdx.x & 63;
  const int wave = threadIdx.x >> 6;
  const int m = lane & 15;
  const int quad = lane >> 4;

  // block decode (big jobs first): sid -> (b, group g, quad-in-group qq, chunk c)
  const int sid = 1151 - (int)blockIdx.x;
  const int b = sid / 288;
  const int rem = sid - b * 288;
  int g = 7;
  while (4 * g * (g + 1) > rem) --g;
  const int t = rem - 4 * g * (g + 1);
  const int qq = t / (g + 1);
  const int c = t - qq * (g + 1);
  const int Q = 8 * g + qq;                     // q-quad 0..63
  const int qt = 4 * Q + wave;                  // this wave's q-tile
  const int q0 = qt * 16;
  const int jid = b * 1152 + 16 * g * (g + 1) + (4 * qq + wave) * (g + 1) + c;
  const int kt0 = 8 * c;
  const int kcR = Q - 8 * c + 1;
  const int kcount = (kcR < 8) ? kcR : 8;       // uniform across waves

  const __hip_bfloat16* qbase = qg + ((size_t)b * T_ + q0 + m) * H_;
  bf16x8 qf0 = *(const bf16x8*)(qbase + quad * 8);
  bf16x8 qf1 = *(const bf16x8*)(qbase + 32 + quad * 8);

  f32x4 Oacc[4];
#pragma unroll
  for (int i = 0; i < 4; ++i) Oacc[i] = (f32x4){0.f, 0.f, 0.f, 0.f};
  float psum = 0.f;

  const __hip_bfloat16* Kb = Kf + (size_t)b * 262144;
  const __hip_bfloat16* vgf = Vf + (size_t)b * 262144 + lane * 8;
  __hip_bfloat16* Plw = &Pl[wave][0];

  __hip_bfloat16* Kcur = &Kl[0][0];
  __hip_bfloat16* Knxt = &Kl[1][0];

  // ---- prologue: stage K tile kt0 (8KB, 2 issues/wave of 1KB)
  {
    const __hip_bfloat16* kp = Kb + (size_t)kt0 * 4096;
#pragma unroll
    for (int i = 0; i < 2; ++i) {
      const int idx = wave * 2 + i;  // 0..7, uniform per wave
      stage16(kp + idx * 512 + lane * 8, Kcur + idx * 512);
    }
  }

  for (int it = 0; it < kcount; ++it) {
    const int ktile = kt0 + it;
    const int k0 = ktile * 64;
    __syncthreads();  // drains vmcnt(0): Kcur staged; prior-iter reads done

    // ---- prefetch next K tile into Knxt (hidden under this iter's compute)
    if (it + 1 < kcount) {
      const __hip_bfloat16* kp = Kb + (size_t)(ktile + 1) * 4096;
#pragma unroll
      for (int i = 0; i < 2; ++i) {
        const int idx = wave * 2 + i;
        stage16(kp + idx * 512 + lane * 8, Knxt + idx * 512);
      }
    }

    // ---- QK^T (S^T formulation) from LDS K frags
    f32x4 s[4];
#pragma unroll
    for (int nt = 0; nt < 4; ++nt) {
      bf16x8 kf0 = *(const bf16x8*)(Kcur + nt * 1024 + lane * 8);
      bf16x8 kf1 = *(const bf16x8*)(Kcur + nt * 1024 + 512 + lane * 8);
      f32x4 tt = (f32x4){0.f, 0.f, 0.f, 0.f};
      tt = __builtin_amdgcn_mfma_f32_16x16x32_bf16(kf0, qf0, tt, 0, 0, 0);
      tt = __builtin_amdgcn_mfma_f32_16x16x32_bf16(kf1, qf1, tt, 0, 0, 0);
      s[nt] = tt;
    }
    // ---- V direct per-wave global reads (natural source position, as R8)
    const __hip_bfloat16* vp = vgf + (size_t)ktile * 4096;
    bf16x8 vf[8];
#pragma unroll
    for (int nt = 0; nt < 4; ++nt) {
      vf[2 * nt] = *(const bf16x8*)(vp + nt * 1024);
      vf[2 * nt + 1] = *(const bf16x8*)(vp + nt * 1024 + 512);
    }

    // ---- static-max softmax (exp2 domain, Q pre-scaled); causal mask
    const bool needmask = (k0 + 63 > q0);
#pragma unroll
    for (int nt = 0; nt < 4; ++nt) {
      float p[4];
#pragma unroll
      for (int r = 0; r < 4; ++r) {
        float sv = s[nt][r];
        if (needmask && (k0 + nt * 16 + quad * 4 + r) > (q0 + m))
          sv = -__builtin_inff();
        p[r] = exp2f(sv);
        psum += p[r];
      }
      uint2 u = {pack2(p[0], p[1]), pack2(p[2], p[3])};
      *(uint2*)(&Plw[m * LSTR + nt * 16 + quad * 4]) = u;
    }

    bf16x8 pf0 = *(const bf16x8*)(&Plw[m * LSTR + quad * 8]);
    bf16x8 pf1 = *(const bf16x8*)(&Plw[m * LSTR + 32 + quad * 8]);
#pragma unroll
    for (int nt = 0; nt < 4; ++nt) {
      Oacc[nt] = __builtin_amdgcn_mfma_f32_16x16x32_bf16(pf0, vf[2 * nt], Oacc[nt], 0, 0, 0);
      Oacc[nt] = __builtin_amdgcn_mfma_f32_16x16x32_bf16(pf1, vf[2 * nt + 1], Oacc[nt], 0, 0, 0);
    }

    // swap K buffers
    __hip_bfloat16* tmp = Kcur; Kcur = Knxt; Knxt = tmp;
  }

  psum += __shfl_xor(psum, 16);
  psum += __shfl_xor(psum, 32);
  // psum at lane l = full row-sum for q-row (l & 15), replicated across quads.

  if (g == 0) {
    // ---- nc==1: direct normalized output (R4-verified path, no fences).
    float Lr[4];
#pragma unroll
    for (int r = 0; r < 4; ++r) Lr[r] = __shfl(psum, quad * 4 + r);
#pragma unroll
    for (int nt = 0; nt < 4; ++nt)
#pragma unroll
      for (int r = 0; r < 4; ++r)
        out[((size_t)b * T_ + q0 + quad * 4 + r) * H_ + nt * 16 + m] =
            Oacc[nt][r] / Lr[r];
  } else {
    // ---- fp16 partials: half the split-K round-trip traffic
    __half* Op = Opart + (size_t)jid * 1024;
#pragma unroll
    for (int nt = 0; nt < 4; ++nt)
#pragma unroll
      for (int r = 0; r < 4; ++r)
        Op[(quad * 4 + r) * 64 + nt * 16 + m] = __float2half(Oacc[nt][r]);
    if (lane < 16) Ml[(size_t)jid * 16 + lane] = __float2half(psum);
  }
}

// ---- kernel 3: combine partials — plain sums, fp16 inputs, qt>=32 only.
__global__ __launch_bounds__(256) void fa_combine(
    const __half* __restrict__ Opart, const __half* __restrict__ Ml,
    float* __restrict__ out) {
  const int bq = blockIdx.x;          // 0..895
  const int b = bq / 224;
  const int qt = (bq - b * 224) + 32; // 32..255
  const int g = qt >> 5;              // 1..7
  const int nc = g + 1;
  const int jbase = b * 1152 + 16 * g * (g + 1) + (qt & 31) * nc;
  const int r = threadIdx.x >> 4;
  const int h0 = (threadIdx.x & 15) * 4;

  float4 O = {0.f, 0.f, 0.f, 0.f};
  float L = 0.f;
  for (int c = 0; c < nc; ++c) {
    L += __half2float(Ml[(size_t)(jbase + c) * 16 + r]);
    const __half2* op =
        (const __half2*)(Opart + (size_t)(jbase + c) * 1024 + r * 64 + h0);
    __half2 o01 = op[0], o23 = op[1];
    O.x += __low2float(o01); O.y += __high2float(o01);
    O.z += __low2float(o23); O.w += __high2float(o23);
  }
  float inv = 1.f / L;
  float4 res = {O.x * inv, O.y * inv, O.z * inv, O.w * inv};
  *(float4*)(out + ((size_t)b * T_ + qt * 16 + r) * H_ + h0) = res;
}

extern "C" void kernel_launch(void* const* d_in, const int* in_sizes, int n_in,
                              void* d_out, int out_size, void* d_ws, size_t ws_size,
                              hipStream_t stream) {
  const float* x = (const float*)d_in[0];
  const float* Wk = (const float*)d_in[1];
  const float* Wq = (const float*)d_in[2];
  const float* Wv = (const float*)d_in[3];
  float* out = (float*)d_out;
  char* ws = (char*)d_ws;
  // ws: Wtf[192*1024]bf16(frag order) | qb[4][4096][64]bf16 | Kf[4][64][4096]bf16
  //     | Vf same | Opart[4608][16][64]f16 | Ml[4608][16]f16
  __hip_bfloat16* Wtf = (__hip_bfloat16*)ws;
  __hip_bfloat16* qb = (__hip_bfloat16*)(ws + 393216);
  __hip_bfloat16* Kf = (__hip_bfloat16*)(ws + 2490368);
  __hip_bfloat16* Vf = (__hip_bfloat16*)(ws + 4587520);
  __half* Opart = (__half*)(ws + 6684672);
  __half* Ml = (__half*)(ws + 16121856);

  hipLaunchKernelGGL(wtrans_kernel, dim3(768), dim3(256), 0, stream, Wk, Wq, Wv, Wtf);
  hipLaunchKernelGGL(proj_kernel, dim3(1024), dim3(256), 0, stream, x, Wtf, qb, Kf, Vf);
  hipLaunchKernelGGL(fa_pass1, dim3(1152), dim3(256), 0, stream, qb, Kf, Vf, Opart, Ml, out);
  hipLaunchKernelGGL(fa_combine, dim3(896), dim3(256), 0, stream, Opart, Ml, out);
}

// Round 13
// 138.494 us; speedup vs baseline: 1.0600x; 1.0600x over previous
//
#include <hip/hip_runtime.h>
#include <hip/hip_bf16.h>
#include <hip/hip_fp16.h>

#define T_ 4096
#define C_ 1024
#define H_ 64
#define LSTR 72    // P-buffer LDS row stride (bf16 elems)
#define XBS 1032   // x-tile LDS row stride (bf16 elems): mult-8 (16B align), 4-way banks max

typedef short bf16x8 __attribute__((ext_vector_type(8)));
typedef float f32x4 __attribute__((ext_vector_type(4)));

__device__ __forceinline__ short f2bf(float f) {
  union { __hip_bfloat16 h; short s; } u;
  u.h = __float2bfloat16(f);
  return u.s;
}
__device__ __forceinline__ unsigned pack2(float a, float b) {
  return ((unsigned)(unsigned short)f2bf(b) << 16) | (unsigned short)f2bf(a);
}

// async global->LDS, 16B per lane; LDS dest = wave-uniform base + lane*16.
__device__ __forceinline__ void stage16(const __hip_bfloat16* g,
                                        __hip_bfloat16* l) {
  __builtin_amdgcn_global_load_lds(
      (const __attribute__((address_space(1))) unsigned*)g,
      (__attribute__((address_space(3))) unsigned*)l, 16, 0, 0);
}

// ---- kernel 0: W[c][h] fp32 -> Wtf in MFMA B-FRAG ORDER (R3-verified).
__global__ void wtrans_kernel(const float* __restrict__ Wk,
                              const float* __restrict__ Wq,
                              const float* __restrict__ Wv,
                              __hip_bfloat16* __restrict__ Wtf) {
  int tid = blockIdx.x * 256 + threadIdx.x;  // 0..196607 exact
  const int j = tid & 7;
  const int lane = (tid >> 3) & 63;
  const int m = lane & 15;
  const int quad = lane >> 4;
  const int f = (tid >> 9) & 15;
  const int nt = f & 3;
  const int ks = f >> 2;
  const int c = (tid >> 13) & 7;
  const int which = tid >> 16;
  const float* W = (which == 0) ? Wk : ((which == 1) ? Wq : Wv);
  const int cc = c * 128 + ks * 32 + quad * 8 + j;
  const int h = nt * 16 + m;
  Wtf[tid] = __float2bfloat16(W[cc * 64 + h]);
}

// ---- kernel 1: qkv projection (exact R0 known-good version).
__global__ __launch_bounds__(256) void proj_kernel(
    const float* __restrict__ x, const __hip_bfloat16* __restrict__ Wtf,
    __hip_bfloat16* __restrict__ qb, __hip_bfloat16* __restrict__ Kf,
    __hip_bfloat16* __restrict__ Vf) {
  __shared__ __hip_bfloat16 Xb[16 * XBS];
  const int tid = threadIdx.x;
  const int lane = tid & 63;
  const int wave = tid >> 6;
  const int m = lane & 15;
  const int quad = lane >> 4;
  const int t0 = blockIdx.x * 16;

  // ---- phase 1: stage x-tile (contiguous 4096 float4), convert to bf16
  const float4* xtile = (const float4*)(x + (size_t)t0 * C_);
  float4 xv[16];
#pragma unroll
  for (int k = 0; k < 16; ++k) xv[k] = xtile[tid + k * 256];
#pragma unroll
  for (int k = 0; k < 16; ++k) {
    const int idx = tid + k * 256;
    const int row = idx >> 8;      // 256 float4 per row
    const int c4 = idx & 255;
    uint2 u = {pack2(xv[k].x, xv[k].y), pack2(xv[k].z, xv[k].w)};
    *(uint2*)(&Xb[row * XBS + c4 * 4]) = u;
  }
  __syncthreads();

  // ---- phase 2: wave owns output-tiles g = 3*wave .. 3*wave+2
  int whichs[3], ntls[3];
  const __hip_bfloat16* wb[3];
#pragma unroll
  for (int i = 0; i < 3; ++i) {
    const int g = wave * 3 + i;
    whichs[i] = g >> 2;
    ntls[i] = g & 3;
    wb[i] = Wtf + (size_t)whichs[i] * 65536 + ntls[i] * 512 + lane * 8;
  }
  f32x4 acc[3];
#pragma unroll
  for (int i = 0; i < 3; ++i) acc[i] = (f32x4){0.f, 0.f, 0.f, 0.f};

#pragma unroll
  for (int c = 0; c < 8; ++c) {
    bf16x8 bq[12];
#pragma unroll
    for (int i = 0; i < 3; ++i)
#pragma unroll
      for (int ks = 0; ks < 4; ++ks)
        bq[i * 4 + ks] = *(const bf16x8*)(wb[i] + (c * 16 + ks * 4) * 512);
#pragma unroll
    for (int ks = 0; ks < 4; ++ks) {
      bf16x8 a = *(const bf16x8*)(&Xb[m * XBS + c * 128 + ks * 32 + quad * 8]);
#pragma unroll
      for (int i = 0; i < 3; ++i)
        acc[i] = __builtin_amdgcn_mfma_f32_16x16x32_bf16(a, bq[i * 4 + ks],
                                                         acc[i], 0, 0, 0);
    }
  }

  // ---- stores
  const int bb = t0 >> 12;
  const int tloc = t0 & (T_ - 1);
  const int ktile = tloc >> 6;
  const float cscale = 0.18033688011112042f;  // log2(e)/sqrt(64)

#pragma unroll
  for (int i = 0; i < 3; ++i) {
    const int which = whichs[i];
    const int ntl = ntls[i];
    if (which == 1) {  // Q: row-major [t][h], PRE-SCALED into exp2 domain
#pragma unroll
      for (int r = 0; r < 4; ++r)
        qb[(size_t)(t0 + quad * 4 + r) * H_ + ntl * 16 + m] =
            __float2bfloat16(acc[i][r] * cscale);
    } else if (which == 0) {  // K -> frag order (R3-verified swizzle)
      __hip_bfloat16* dst = Kf + ((size_t)bb * 64 + ktile) * 4096;
      const int ntK = (tloc >> 4) & 3;
      const int wh = ntl >> 1;
      const int quadK = (ntl * 2 + (m >> 3)) & 3;
      const int j = m & 7;
#pragma unroll
      for (int r = 0; r < 4; ++r) {
        const int mK = quad * 4 + r;
        dst[(ntK * 2 + wh) * 512 + (quadK * 16 + mK) * 8 + j] =
            __float2bfloat16(acc[i][r]);
      }
    } else {  // V -> frag order (R3-verified swizzle)
      __hip_bfloat16* dst = Vf + ((size_t)bb * 64 + ktile) * 4096;
#pragma unroll
      for (int r = 0; r < 4; ++r) {
        const int kvo = (tloc & 63) + quad * 4 + r;
        const int half = (kvo >> 5) & 1;
        const int quadV = (kvo >> 3) & 3;
        const int j = kvo & 7;
        dst[(ntl * 2 + half) * 512 + (quadV * 16 + m) * 8 + j] =
            __float2bfloat16(acc[i][r]);
      }
    }
  }
}

// ---- kernel 2: flash pass1 v12 (R13): EXACT R8 champion loop + bounds
// ((256,5), K-only dbuf, V direct reads, 1 barrier/iter, fp16 partials).
// Single delta vs R8: nc==1 (g==0, qt<32) jobs normalize in-register (shfl
// transpose, R4-verified) and write out directly — removes their Opart/Ml
// round-trip; combine shrinks to qt>=32. R12's (256,6) occupancy raise is
// REVERTED (implicated in its -7us regression; R9-R12 showed this loop is a
// sharp local optimum at 5 blocks/CU).
__global__ __launch_bounds__(256, 5) void fa_pass1(
    const __hip_bfloat16* __restrict__ qg, const __hip_bfloat16* __restrict__ Kf,
    const __hip_bfloat16* __restrict__ Vf, __half* __restrict__ Opart,
    __half* __restrict__ Ml, float* __restrict__ out) {
  __shared__ __align__(16) __hip_bfloat16 Kl[2][4096];  // K tile dbuf, 8KB each
  __shared__ __hip_bfloat16 Pl[4][16 * LSTR];           // P[q=16][kv=64] per wave
  const int lane = threadIdx.x & 63;
  const int wave = threadIdx.x >> 6;
  const int m = lane & 15;
  const int quad = lane >> 4;

  // block decode (big jobs first): sid -> (b, group g, quad-in-group qq, chunk c)
  const int sid = 1151 - (int)blockIdx.x;
  const int b = sid / 288;
  const int rem = sid - b * 288;
  int g = 7;
  while (4 * g * (g + 1) > rem) --g;
  const int t = rem - 4 * g * (g + 1);
  const int qq = t / (g + 1);
  const int c = t - qq * (g + 1);
  const int Q = 8 * g + qq;                     // q-quad 0..63
  const int qt = 4 * Q + wave;                  // this wave's q-tile
  const int q0 = qt * 16;
  const int jid = b * 1152 + 16 * g * (g + 1) + (4 * qq + wave) * (g + 1) + c;
  const int kt0 = 8 * c;
  const int kcR = Q - 8 * c + 1;
  const int kcount = (kcR < 8) ? kcR : 8;       // uniform across waves

  const __hip_bfloat16* qbase = qg + ((size_t)b * T_ + q0 + m) * H_;
  bf16x8 qf0 = *(const bf16x8*)(qbase + quad * 8);
  bf16x8 qf1 = *(const bf16x8*)(qbase + 32 + quad * 8);

  f32x4 Oacc[4];
#pragma unroll
  for (int i = 0; i < 4; ++i) Oacc[i] = (f32x4){0.f, 0.f, 0.f, 0.f};
  float psum = 0.f;

  const __hip_bfloat16* Kb = Kf + (size_t)b * 262144;
  const __hip_bfloat16* vgf = Vf + (size_t)b * 262144 + lane * 8;
  __hip_bfloat16* Plw = &Pl[wave][0];

  __hip_bfloat16* Kcur = &Kl[0][0];
  __hip_bfloat16* Knxt = &Kl[1][0];

  // ---- prologue: stage K tile kt0 (8KB, 2 issues/wave of 1KB)
  {
    const __hip_bfloat16* kp = Kb + (size_t)kt0 * 4096;
#pragma unroll
    for (int i = 0; i < 2; ++i) {
      const int idx = wave * 2 + i;  // 0..7, uniform per wave
      stage16(kp + idx * 512 + lane * 8, Kcur + idx * 512);
    }
  }

  for (int it = 0; it < kcount; ++it) {
    const int ktile = kt0 + it;
    const int k0 = ktile * 64;
    __syncthreads();  // drains vmcnt(0): Kcur staged; prior-iter reads done

    // ---- prefetch next K tile into Knxt (hidden under this iter's compute)
    if (it + 1 < kcount) {
      const __hip_bfloat16* kp = Kb + (size_t)(ktile + 1) * 4096;
#pragma unroll
      for (int i = 0; i < 2; ++i) {
        const int idx = wave * 2 + i;
        stage16(kp + idx * 512 + lane * 8, Knxt + idx * 512);
      }
    }

    // ---- QK^T (S^T formulation) from LDS K frags
    f32x4 s[4];
#pragma unroll
    for (int nt = 0; nt < 4; ++nt) {
      bf16x8 kf0 = *(const bf16x8*)(Kcur + nt * 1024 + lane * 8);
      bf16x8 kf1 = *(const bf16x8*)(Kcur + nt * 1024 + 512 + lane * 8);
      f32x4 tt = (f32x4){0.f, 0.f, 0.f, 0.f};
      tt = __builtin_amdgcn_mfma_f32_16x16x32_bf16(kf0, qf0, tt, 0, 0, 0);
      tt = __builtin_amdgcn_mfma_f32_16x16x32_bf16(kf1, qf1, tt, 0, 0, 0);
      s[nt] = tt;
    }
    // ---- V direct per-wave global reads (natural source position, as R8)
    const __hip_bfloat16* vp = vgf + (size_t)ktile * 4096;
    bf16x8 vf[8];
#pragma unroll
    for (int nt = 0; nt < 4; ++nt) {
      vf[2 * nt] = *(const bf16x8*)(vp + nt * 1024);
      vf[2 * nt + 1] = *(const bf16x8*)(vp + nt * 1024 + 512);
    }

    // ---- static-max softmax (exp2 domain, Q pre-scaled); causal mask
    const bool needmask = (k0 + 63 > q0);
#pragma unroll
    for (int nt = 0; nt < 4; ++nt) {
      float p[4];
#pragma unroll
      for (int r = 0; r < 4; ++r) {
        float sv = s[nt][r];
        if (needmask && (k0 + nt * 16 + quad * 4 + r) > (q0 + m))
          sv = -__builtin_inff();
        p[r] = exp2f(sv);
        psum += p[r];
      }
      uint2 u = {pack2(p[0], p[1]), pack2(p[2], p[3])};
      *(uint2*)(&Plw[m * LSTR + nt * 16 + quad * 4]) = u;
    }

    bf16x8 pf0 = *(const bf16x8*)(&Plw[m * LSTR + quad * 8]);
    bf16x8 pf1 = *(const bf16x8*)(&Plw[m * LSTR + 32 + quad * 8]);
#pragma unroll
    for (int nt = 0; nt < 4; ++nt) {
      Oacc[nt] = __builtin_amdgcn_mfma_f32_16x16x32_bf16(pf0, vf[2 * nt], Oacc[nt], 0, 0, 0);
      Oacc[nt] = __builtin_amdgcn_mfma_f32_16x16x32_bf16(pf1, vf[2 * nt + 1], Oacc[nt], 0, 0, 0);
    }

    // swap K buffers
    __hip_bfloat16* tmp = Kcur; Kcur = Knxt; Knxt = tmp;
  }

  psum += __shfl_xor(psum, 16);
  psum += __shfl_xor(psum, 32);
  // psum at lane l = full row-sum for q-row (l & 15), replicated across quads.

  if (g == 0) {
    // ---- nc==1: direct normalized output (R4-verified path, no fences).
    float Lr[4];
#pragma unroll
    for (int r = 0; r < 4; ++r) Lr[r] = __shfl(psum, quad * 4 + r);
#pragma unroll
    for (int nt = 0; nt < 4; ++nt)
#pragma unroll
      for (int r = 0; r < 4; ++r)
        out[((size_t)b * T_ + q0 + quad * 4 + r) * H_ + nt * 16 + m] =
            Oacc[nt][r] / Lr[r];
  } else {
    // ---- fp16 partials: half the split-K round-trip traffic
    __half* Op = Opart + (size_t)jid * 1024;
#pragma unroll
    for (int nt = 0; nt < 4; ++nt)
#pragma unroll
      for (int r = 0; r < 4; ++r)
        Op[(quad * 4 + r) * 64 + nt * 16 + m] = __float2half(Oacc[nt][r]);
    if (lane < 16) Ml[(size_t)jid * 16 + lane] = __float2half(psum);
  }
}

// ---- kernel 3: combine partials — plain sums, fp16 inputs, qt>=32 only.
__global__ __launch_bounds__(256) void fa_combine(
    const __half* __restrict__ Opart, const __half* __restrict__ Ml,
    float* __restrict__ out) {
  const int bq = blockIdx.x;          // 0..895
  const int b = bq / 224;
  const int qt = (bq - b * 224) + 32; // 32..255
  const int g = qt >> 5;              // 1..7
  const int nc = g + 1;
  const int jbase = b * 1152 + 16 * g * (g + 1) + (qt & 31) * nc;
  const int r = threadIdx.x >> 4;
  const int h0 = (threadIdx.x & 15) * 4;

  float4 O = {0.f, 0.f, 0.f, 0.f};
  float L = 0.f;
  for (int c = 0; c < nc; ++c) {
    L += __half2float(Ml[(size_t)(jbase + c) * 16 + r]);
    const __half2* op =
        (const __half2*)(Opart + (size_t)(jbase + c) * 1024 + r * 64 + h0);
    __half2 o01 = op[0], o23 = op[1];
    O.x += __low2float(o01); O.y += __high2float(o01);
    O.z += __low2float(o23); O.w += __high2float(o23);
  }
  float inv = 1.f / L;
  float4 res = {O.x * inv, O.y * inv, O.z * inv, O.w * inv};
  *(float4*)(out + ((size_t)b * T_ + qt * 16 + r) * H_ + h0) = res;
}

extern "C" void kernel_launch(void* const* d_in, const int* in_sizes, int n_in,
                              void* d_out, int out_size, void* d_ws, size_t ws_size,
                              hipStream_t stream) {
  const float* x = (const float*)d_in[0];
  const float* Wk = (const float*)d_in[1];
  const float* Wq = (const float*)d_in[2];
  const float* Wv = (const float*)d_in[3];
  float* out = (float*)d_out;
  char* ws = (char*)d_ws;
  // ws: Wtf[192*1024]bf16(frag order) | qb[4][4096][64]bf16 | Kf[4][64][4096]bf16
  //     | Vf same | Opart[4608][16][64]f16 | Ml[4608][16]f16
  __hip_bfloat16* Wtf = (__hip_bfloat16*)ws;
  __hip_bfloat16* qb = (__hip_bfloat16*)(ws + 393216);
  __hip_bfloat16* Kf = (__hip_bfloat16*)(ws + 2490368);
  __hip_bfloat16* Vf = (__hip_bfloat16*)(ws + 4587520);
  __half* Opart = (__half*)(ws + 6684672);
  __half* Ml = (__half*)(ws + 16121856);

  hipLaunchKernelGGL(wtrans_kernel, dim3(768), dim3(256), 0, stream, Wk, Wq, Wv, Wtf);
  hipLaunchKernelGGL(proj_kernel, dim3(1024), dim3(256), 0, stream, x, Wtf, qb, Kf, Vf);
  hipLaunchKernelGGL(fa_pass1, dim3(1152), dim3(256), 0, stream, qb, Kf, Vf, Opart, Ml, out);
  hipLaunchKernelGGL(fa_combine, dim3(896), dim3(256), 0, stream, Opart, Ml, out);
}